// Round 14
// baseline (183.571 us; speedup 1.0000x reference)
//
#include <hip/hip_runtime.h>

// Problem constants
#define B_  2
#define S_  2048
#define D_  1024
#define H_  16
#define HD_ 64
#define N3_ 3072      // 3*D
#define M_  4096      // B*S

typedef _Float16 f16;
typedef _Float16 f16x2 __attribute__((ext_vector_type(2)));
typedef _Float16 f16x4 __attribute__((ext_vector_type(4)));
typedef _Float16 f16x8 __attribute__((ext_vector_type(8)));
typedef float    f32x4 __attribute__((ext_vector_type(4)));

// ---------------------------------------------------------------------------
// async global->LDS, 16B per lane. LDS dest must be wave-uniform base+lane*16.
__device__ __forceinline__ void async16(const f16* g, f16* l) {
  __builtin_amdgcn_global_load_lds(
      (const __attribute__((address_space(1))) unsigned int*)g,
      (__attribute__((address_space(3))) unsigned int*)l, 16, 0, 0);
}

__device__ __forceinline__ f16x2 pkrtz(float a, float b) {
  return __builtin_bit_cast(f16x2, __builtin_amdgcn_cvt_pkrtz(a, b));
}

// Raw v_exp_f32 (2^x). exp2f without fast-math expands to ~6-inst libm
// range-fixup; scores here are bounded and masked lanes (-1e30) flush to 0.
__device__ __forceinline__ float vexp2(float x) {
  float r; asm("v_exp_f32 %0, %1" : "=v"(r) : "v"(x)); return r;
}

// ---------------------------------------------------------------------------
// One launch converts x AND all 4 weight matrices to f16.
__global__ __launch_bounds__(256)
void cvt_all(const float* __restrict__ x,
             const float* __restrict__ Wq, const float* __restrict__ Wk,
             const float* __restrict__ Wv, const float* __restrict__ Wo,
             f16* __restrict__ xb, f16* __restrict__ wdst, float qscale) {
  const int i = blockIdx.x * 256 + threadIdx.x;
  const int XN4 = M_ * D_ / 4;          // 1048576
  const int WN4 = D_ * D_ / 4;          // 262144 = 2^18
  const float* src;
  f16* dst;
  float scale = 1.0f;
  int j;
  if (i < XN4) {
    src = x; dst = xb; j = i;
  } else {
    int k = i - XN4;
    int m = k >> 18;                    // which weight matrix
    j = k & (WN4 - 1);
    src = (m == 0) ? Wq : (m == 1) ? Wk : (m == 2) ? Wv : Wo;
    if (m == 0) scale = qscale;
    dst = wdst + (size_t)m * D_ * D_;
  }
  float4 v = ((const float4*)src)[j];
  f16x4 o = { (f16)(v.x * scale), (f16)(v.y * scale),
              (f16)(v.z * scale), (f16)(v.w * scale) };
  ((f16x4*)dst)[j] = o;
}

// ---------------------------------------------------------------------------
// QKV GEMM v4 (r10 measured-good): 64x128 tile, 48KB dbuf, grid 1536 =
// 6 blocks/CU over 3-resident capacity = two FULL residency rounds, no tail.
// Counted-vmcnt dbuf (vmcnt(6)), raw s_barrier, XCD chunk 16Mx12N.
__global__ __launch_bounds__(256)
void gemm_qkv(const f16* __restrict__ A, const f16* __restrict__ Bw,
              f16* __restrict__ Cq, f16* __restrict__ vtout,
              const float* __restrict__ mask) {
  __shared__ f16 As0[64 * 64];
  __shared__ f16 Bs0[128 * 64];
  __shared__ f16 As1[64 * 64];
  __shared__ f16 Bs1[128 * 64];

  const int tid  = threadIdx.x;
  const int lane = tid & 63;
  const int w    = tid >> 6;
  const int lcol = lane & 15;
  const int quad = lane >> 4;
  const int lx   = lcol & 7;
  const int wave_m = w >> 1, wave_n = w & 1;

  // XCD-chunked swizzle: 1536 = 8 XCDs x 192; per XCD 16 M x 12 N tiles.
  const int lin  = blockIdx.x;
  const int xcd  = lin & 7;
  const int c    = lin >> 3;             // 0..191
  const int mIdx = c / 12;               // 0..15
  const int nIdx = c - mIdx * 12;        // 0..11
  const int m0 = ((xcd >> 1) * 16 + mIdx) * 64;
  const int n0 = ((xcd & 1) * 12 + nIdx) * 128;

  const int rr  = lane >> 3;
  const int gch = (lane & 7) ^ rr;

  const f16* gA[2];
  const f16* gB[4];
#pragma unroll
  for (int i = 0; i < 2; i++) {
    int seg = 2 * w + i;
    gA[i] = A + (size_t)(m0 + seg * 8 + rr) * D_ + gch * 8;
  }
#pragma unroll
  for (int i = 0; i < 4; i++) {
    int seg = i * 4 + w;
    gB[i] = Bw + (size_t)(n0 + seg * 8 + rr) * D_ + gch * 8;
  }

  int offA[2], offB[4];
#pragma unroll
  for (int i = 0; i < 2; i++) offA[i] = (wave_m * 32 + i * 16 + lcol) * 64;
#pragma unroll
  for (int i = 0; i < 4; i++) offB[i] = (wave_n * 64 + i * 16 + lcol) * 64;

  const f32x4 zero = {0.f, 0.f, 0.f, 0.f};
  f32x4 acc[2][4];
#pragma unroll
  for (int i = 0; i < 2; i++)
#pragma unroll
    for (int j = 0; j < 4; j++) acc[i][j] = zero;

  auto stage = [&](int k0, f16* sA, f16* sB) {
#pragma unroll
    for (int i = 0; i < 2; i++) async16(gA[i] + k0, sA + (2 * w + i) * 512);
#pragma unroll
    for (int i = 0; i < 4; i++) async16(gB[i] + k0, sB + (i * 4 + w) * 512);
  };
  auto compute = [&](const f16* sA, const f16* sB) {
#pragma unroll
    for (int ks = 0; ks < 2; ks++) {
      const int co = ((quad + 4 * ks) ^ lx) * 8;
      f16x8 af[2], bf[4];
#pragma unroll
      for (int i = 0; i < 2; i++) af[i] = *(const f16x8*)(sA + offA[i] + co);
#pragma unroll
      for (int i = 0; i < 4; i++) bf[i] = *(const f16x8*)(sB + offB[i] + co);
#pragma unroll
      for (int mi = 0; mi < 2; mi++)
#pragma unroll
        for (int ni = 0; ni < 4; ni++)
          acc[mi][ni] = __builtin_amdgcn_mfma_f32_16x16x32_f16(
              af[mi], bf[ni], acc[mi][ni], 0, 0, 0);
    }
  };

  // K pipeline: 16 tiles of BK=64, even->buf0, odd->buf1. Each stage issues
  // 6 loads/wave; vmcnt(6) waits for the PREVIOUS stage's 6 (issued one full
  // compute phase earlier). Every wave waits before s_barrier, so the buffer
  // is complete device-wide.
  stage(0, As0, Bs0);
  for (int it = 0; it < 14; it += 2) {
    stage((it + 1) * 64, As1, Bs1);
    asm volatile("s_waitcnt vmcnt(6)\ns_barrier" ::: "memory");
    compute(As0, Bs0);
    asm volatile("s_barrier" ::: "memory");      // buf0 readers done
    stage((it + 2) * 64, As0, Bs0);
    asm volatile("s_waitcnt vmcnt(6)\ns_barrier" ::: "memory");
    compute(As1, Bs1);
    asm volatile("s_barrier" ::: "memory");      // buf1 readers done
  }
  stage(15 * 64, As1, Bs1);
  asm volatile("s_waitcnt vmcnt(6)\ns_barrier" ::: "memory");
  compute(As0, Bs0);                              // tile 14
  asm volatile("s_waitcnt vmcnt(0)\ns_barrier" ::: "memory");
  compute(As1, Bs1);                              // tile 15

  // Epilogue: n0 is a multiple of 128 -> whole tile in one region.
#pragma unroll
  for (int mi = 0; mi < 2; mi++) {
    const int mgb = m0 + wave_m * 32 + mi * 16 + quad * 4;
    const int bb = mgb >> 11, s = mgb & (S_ - 1);
    const float mk0 = mask[mgb], mk1 = mask[mgb + 1];
    const float mk2 = mask[mgb + 2], mk3 = mask[mgb + 3];
    const float mks[4] = {mk0, mk1, mk2, mk3};
    if (n0 >= 2 * D_) {
      // V column-block: fused transpose with pad mask.
#pragma unroll
      for (int ni = 0; ni < 4; ni++) {
        const int vcol = n0 - 2 * D_ + wave_n * 64 + ni * 16 + lcol;
        f16x4 v = { (f16)(acc[mi][ni][0] * mk0), (f16)(acc[mi][ni][1] * mk1),
                    (f16)(acc[mi][ni][2] * mk2), (f16)(acc[mi][ni][3] * mk3) };
        *(f16x4*)(vtout +
                  ((size_t)(bb * 16 + (vcol >> 6)) * 64 + (vcol & 63)) * S_ + s) = v;
      }
    } else {
      const bool kmask = (n0 >= D_);
#pragma unroll
      for (int r = 0; r < 4; r++) {
        const float mk = kmask ? mks[r] : 1.0f;
#pragma unroll
        for (int ni = 0; ni < 4; ni++) {
          int ng = n0 + wave_n * 64 + ni * 16 + lcol;
          Cq[(size_t)(mgb + r) * N3_ + ng] = (f16)(acc[mi][ni][r] * mk);
        }
      }
    }
  }
}

// ---------------------------------------------------------------------------
// Output-projection GEMM v3: attn_combine FUSED. Key alignment: proj's
// K-step (64) == one head's hd-block, and 64-row M-tiles == q-supertiles,
// so a big-tile A-panel [64 rows x k0..k0+64] is EXACTLY one part-slot pair
// (sA,sB) of head h=k0/64. Blocks whose M-tile is in rows [1024,2048) per
// batch (block-uniform) stage A by reading both f32 partials, combining
// (oA+oB)/(lpA+lpB), cvt f16, and ds_write into As with the SAME XOR-chunk
// layout async16 produces: As[r*64 + (ch^(r&7))*8] (verified against the
// compute-side read map). Big blocks use the plain single-buffer 2-barrier
// loop (counted-vmcnt bookkeeping would be corrupted by the interleaved f32
// loads); small blocks keep the r11 pipelined path verbatim. Saves the
// 4.3us combine kernel + one launch gap.
__global__ __launch_bounds__(256)
void gemm_proj(const f16* __restrict__ A, const f16* __restrict__ Bw,
               float* __restrict__ Cf, const float* __restrict__ bias,
               const float* __restrict__ part) {
  __shared__ f16 As0[64 * 64];
  __shared__ f16 Bs0[128 * 64];
  __shared__ f16 As1[64 * 64];
  __shared__ f16 Bs1[128 * 64];

  const int tid  = threadIdx.x;
  const int lane = tid & 63;
  const int w    = tid >> 6;
  const int lcol = lane & 15;
  const int quad = lane >> 4;
  const int lx   = lcol & 7;
  const int wave_m = w >> 1, wave_n = w & 1;

  // XCD-chunked swizzle: 512 = 8 XCDs x 64; per XCD 16 M x 4 N tiles.
  const int lin  = blockIdx.x;
  const int xcd  = lin & 7;
  const int c    = lin >> 3;             // 0..63
  const int mIdx = c >> 2;               // 0..15
  const int nIdx = c & 3;                // 0..3
  const int m0 = ((xcd >> 1) * 16 + mIdx) * 64;
  const int n0 = ((xcd & 1) * 4 + nIdx) * 128;

  const int rr  = lane >> 3;
  const int gch = (lane & 7) ^ rr;

  const f16* gA[2];
  const f16* gB[4];
#pragma unroll
  for (int i = 0; i < 2; i++) {
    int seg = 2 * w + i;
    gA[i] = A + (size_t)(m0 + seg * 8 + rr) * D_ + gch * 8;
  }
#pragma unroll
  for (int i = 0; i < 4; i++) {
    int seg = i * 4 + w;
    gB[i] = Bw + (size_t)(n0 + seg * 8 + rr) * D_ + gch * 8;
  }

  int offA[2], offB[4];
#pragma unroll
  for (int i = 0; i < 2; i++) offA[i] = (wave_m * 32 + i * 16 + lcol) * 64;
#pragma unroll
  for (int i = 0; i < 4; i++) offB[i] = (wave_n * 64 + i * 16 + lcol) * 64;

  const f32x4 zero = {0.f, 0.f, 0.f, 0.f};
  f32x4 acc[2][4];
#pragma unroll
  for (int i = 0; i < 2; i++)
#pragma unroll
    for (int j = 0; j < 4; j++) acc[i][j] = zero;

  auto stage = [&](int k0, f16* sA, f16* sB) {
#pragma unroll
    for (int i = 0; i < 2; i++) async16(gA[i] + k0, sA + (2 * w + i) * 512);
#pragma unroll
    for (int i = 0; i < 4; i++) async16(gB[i] + k0, sB + (i * 4 + w) * 512);
  };
  auto compute = [&](const f16* sA, const f16* sB) {
#pragma unroll
    for (int ks = 0; ks < 2; ks++) {
      const int co = ((quad + 4 * ks) ^ lx) * 8;
      f16x8 af[2], bf[4];
#pragma unroll
      for (int i = 0; i < 2; i++) af[i] = *(const f16x8*)(sA + offA[i] + co);
#pragma unroll
      for (int i = 0; i < 4; i++) bf[i] = *(const f16x8*)(sB + offB[i] + co);
#pragma unroll
      for (int mi = 0; mi < 2; mi++)
#pragma unroll
        for (int ni = 0; ni < 4; ni++)
          acc[mi][ni] = __builtin_amdgcn_mfma_f32_16x16x32_f16(
              af[mi], bf[ni], acc[mi][ni], 0, 0, 0);
    }
  };

  const bool bigA = ((m0 & (S_ - 1)) >= 1024);

  if (!bigA) {
    // Small-tile rows: r11 pipelined path verbatim.
    stage(0, As0, Bs0);
    for (int it = 0; it < 14; it += 2) {
      stage((it + 1) * 64, As1, Bs1);
      asm volatile("s_waitcnt vmcnt(6)\ns_barrier" ::: "memory");
      compute(As0, Bs0);
      asm volatile("s_barrier" ::: "memory");      // buf0 readers done
      stage((it + 2) * 64, As0, Bs0);
      asm volatile("s_waitcnt vmcnt(6)\ns_barrier" ::: "memory");
      compute(As1, Bs1);
      asm volatile("s_barrier" ::: "memory");      // buf1 readers done
    }
    stage(15 * 64, As1, Bs1);
    asm volatile("s_waitcnt vmcnt(6)\ns_barrier" ::: "memory");
    compute(As0, Bs0);                              // tile 14
    asm volatile("s_waitcnt vmcnt(0)\ns_barrier" ::: "memory");
    compute(As1, Bs1);                              // tile 15
  } else {
    // Big-tile rows: A comes from the two flash partials; combine on the fly.
    const int bb = m0 >> 11;                    // batch
    const int g  = (m0 & (S_ - 1)) >> 6;        // 16..31
    const int p  = 31 - g;
    const int r  = tid >> 2;                    // 0..63 (row in tile)
    const int c16 = (tid & 3) * 16;             // col base (0,16,32,48)
    const int ch0 = (tid & 3) * 2;              // first 8-col chunk index
    const int rx  = r & 7;

    for (int k0 = 0; k0 < D_; k0 += 64) {
      const int h = k0 >> 6;
      const float* sA = part + ((size_t)((bb * 16 + h) * 16 + p) * 2 + 0) * 4160;
      const float* sB = sA + 4160;

      __syncthreads();                          // As0/Bs0 readers done
#pragma unroll
      for (int i = 0; i < 4; i++) async16(gB[i] + k0, Bs0 + (i * 4 + w) * 512);

      const float inv = 1.f / (sA[4096 + r] + sB[4096 + r]);
      f32x4 va[4], vb[4];
#pragma unroll
      for (int j = 0; j < 4; j++) {
        va[j] = *(const f32x4*)(sA + r * 64 + c16 + j * 4);
        vb[j] = *(const f32x4*)(sB + r * 64 + c16 + j * 4);
      }
      f16x8 lo, hi;
#pragma unroll
      for (int j = 0; j < 2; j++)
#pragma unroll
        for (int e = 0; e < 4; e++)
          lo[j * 4 + e] = (f16)((va[j][e] + vb[j][e]) * inv);
#pragma unroll
      for (int j = 0; j < 2; j++)
#pragma unroll
        for (int e = 0; e < 4; e++)
          hi[j * 4 + e] = (f16)((va[2 + j][e] + vb[2 + j][e]) * inv);
      *(f16x8*)(As0 + r * 64 + ((ch0 ^ rx)) * 8)       = lo;
      *(f16x8*)(As0 + r * 64 + (((ch0 + 1) ^ rx)) * 8) = hi;

      __syncthreads();                          // staging complete (vmcnt+lgkm)
      compute(As0, Bs0);
    }
  }

#pragma unroll
  for (int mi = 0; mi < 2; mi++) {
#pragma unroll
    for (int r = 0; r < 4; r++) {
      int mg = m0 + wave_m * 32 + mi * 16 + quad * 4 + r;
#pragma unroll
      for (int ni = 0; ni < 4; ni++) {
        int ng = n0 + wave_n * 64 + ni * 16 + lcol;
        Cf[(size_t)mg * D_ + ng] = acc[mi][ni][r] + bias[ng];
      }
    }
  }
}

// ---------------------------------------------------------------------------
// Flash attention v8 (r11/r13 measured-best): 32 q-rows PER WAVE (2
// q-subtiles), 2 waves per block (128 threads). K/V fragments are
// q-independent -> each LDS fragment read feeds TWO MFMA pairs. Raw
// v_exp_f32 softmax. Grid 1024, A/B equal-work role split, XCD swizzle on
// id&31. Big-tile partials go to `part`; combine now fused into gemm_proj.
__global__ __launch_bounds__(128)
void flash_attn8(const f16* __restrict__ qkv, const f16* __restrict__ vt,
                 f16* __restrict__ ctx, float* __restrict__ part) {
  __shared__ f16 Ks[64 * 64];   // [key][hd], 128B rows, chunk-swizzled
  __shared__ f16 Vs[64 * 64];   // [hd][key]

  const int tid  = threadIdx.x;
  const int lane = tid & 63;
  const int w    = tid >> 6;     // 0..1
  const int lcol = lane & 15;
  const int quad = lane >> 4;
  const int lx   = lcol & 7;

  const int id   = blockIdx.x;
  const int bh   = (id & 7) + 8 * ((id >> 3) & 3);  // XCD swizzle (id&31 only)
  const int u    = id >> 5;          // 0..31
  const int p    = u & 15;           // pair index
  const int role = u >> 4;           // 0 = A, 1 = B
  const int g    = 31 - p;           // big q-supertile (>= 16)
  const int b    = bh >> 4, h = bh & 15;

  const int rsub = lane >> 3;
  const int gch  = (lane & 7) ^ rsub;
  const f16* Kg = qkv + (size_t)b * S_ * N3_ + D_ + h * HD_;  // row stride N3
  const f16* Vg = vt + (size_t)bh * HD_ * S_;                 // row stride S

  // This wave stages 4 of the 8 row-groups (8 rows each) of K and V.
  int srow[4];
  f16 *ldsK[4], *ldsV[4];
#pragma unroll
  for (int i = 0; i < 4; i++) {
    const int r0 = w * 32 + i * 8;
    srow[i] = r0 + rsub;
    ldsK[i] = Ks + r0 * 64;
    ldsV[i] = Vs + r0 * 64;
  }

  const f32x4 zero = {0.f, 0.f, 0.f, 0.f};
  f32x4 o0[4], o1[4];
  float lp0, lp1;

  auto run = [&](int qt, int ktb, int kte) {
    const int qrow0 = qt * 64 + w * 32 + lcol;        // subtile 0
    const int qrow1 = qrow0 + 16;                     // subtile 1
    const f16* Qp0 = qkv + (size_t)(b * S_ + qrow0) * N3_ + h * HD_;
    const f16* Qp1 = qkv + (size_t)(b * S_ + qrow1) * N3_ + h * HD_;
    const f16x8 qa0 = *(const f16x8*)(Qp0 + quad * 8);
    const f16x8 qa1 = *(const f16x8*)(Qp0 + 32 + quad * 8);
    const f16x8 qb0 = *(const f16x8*)(Qp1 + quad * 8);
    const f16x8 qb1 = *(const f16x8*)(Qp1 + 32 + quad * 8);
#pragma unroll
    for (int i = 0; i < 4; i++) { o0[i] = zero; o1[i] = zero; }
    lp0 = 0.f; lp1 = 0.f;

    for (int kt = ktb; kt < kte; kt++) {
      const int kbase = kt * 64;
      __syncthreads();
#pragma unroll
      for (int i = 0; i < 4; i++)
        async16(Kg + (size_t)(kbase + srow[i]) * N3_ + gch * 8, ldsK[i]);
#pragma unroll
      for (int i = 0; i < 4; i++)
        async16(Vg + (size_t)srow[i] * S_ + kbase + gch * 8, ldsV[i]);
      __syncthreads();

      f32x4 sc0[4], sc1[4];
#pragma unroll
      for (int ct = 0; ct < 4; ct++) {
        const f16* kr = Ks + (ct * 16 + lcol) * 64;
        f16x8 kf0 = *(const f16x8*)(kr + ((quad    ) ^ lx) * 8);
        f16x8 kf1 = *(const f16x8*)(kr + ((quad + 4) ^ lx) * 8);
        f32x4 z0 = zero;
        z0 = __builtin_amdgcn_mfma_f32_16x16x32_f16(kf0, qa0, z0, 0, 0, 0);
        z0 = __builtin_amdgcn_mfma_f32_16x16x32_f16(kf1, qa1, z0, 0, 0, 0);
        sc0[ct] = z0;
        f32x4 z1 = zero;
        z1 = __builtin_amdgcn_mfma_f32_16x16x32_f16(kf0, qb0, z1, 0, 0, 0);
        z1 = __builtin_amdgcn_mfma_f32_16x16x32_f16(kf1, qb1, z1, 0, 0, 0);
        sc1[ct] = z1;
      }

      if (kt == qt) {
        const int qoff0 = w * 32 + lcol;
        const int qoff1 = qoff0 + 16;
#pragma unroll
        for (int ct = 0; ct < 4; ct++) {
          const int koff = ct * 16 + quad * 4;
#pragma unroll
          for (int r = 0; r < 4; r++) {
            if (koff + r > qoff0) sc0[ct][r] = -1e30f;
            if (koff + r > qoff1) sc1[ct][r] = -1e30f;
          }
        }
      }

      f16x4 pf0[4], pf1[4];
#pragma unroll
      for (int ct = 0; ct < 4; ct++) {
        float a0 = vexp2(sc0[ct][0]), a1 = vexp2(sc0[ct][1]);
        float a2 = vexp2(sc0[ct][2]), a3 = vexp2(sc0[ct][3]);
        lp0 += (a0 + a1) + (a2 + a3);
        f16x2 alo = pkrtz(a0, a1);
        f16x2 ahi = pkrtz(a2, a3);
        f16x4 pa = { alo[0], alo[1], ahi[0], ahi[1] };
        pf0[ct] = pa;
        float b0 = vexp2(sc1[ct][0]), b1 = vexp2(sc1[ct][1]);
        float b2 = vexp2(sc1[ct][2]), b3 = vexp2(sc1[ct][3]);
        lp1 += (b0 + b1) + (b2 + b3);
        f16x2 blo = pkrtz(b0, b1);
        f16x2 bhi = pkrtz(b2, b3);
        f16x4 pb = { blo[0], blo[1], bhi[0], bhi[1] };
        pf1[ct] = pb;
      }

#pragma unroll
      for (int ht = 0; ht < 4; ht++) {
        const f16* vr = Vs + (ht * 16 + lcol) * 64 + (quad & 1) * 4;
#pragma unroll
        for (int ct = 0; ct < 4; ct++) {
          f16x4 vf = *(const f16x4*)(vr + (((2 * ct + (quad >> 1)) ^ lx) * 8));
          o0[ht] = __builtin_amdgcn_mfma_f32_16x16x16f16(vf, pf0[ct], o0[ht], 0, 0, 0);
          o1[ht] = __builtin_amdgcn_mfma_f32_16x16x16f16(vf, pf1[ct], o1[ht], 0, 0, 0);
        }
      }
    }
    lp0 += __shfl_xor(lp0, 16);
    lp0 += __shfl_xor(lp0, 32);
    lp1 += __shfl_xor(lp1, 16);
    lp1 += __shfl_xor(lp1, 32);
  };

  const int row0 = w * 32 + lcol;          // row within 64-row tile, sub 0
  const int row1 = row0 + 16;              // sub 1

  if (role == 0) {
    // A: big tile, first 16 key-tiles (never diagonal). Partial out.
    run(g, 0, 16);
    float* slot = part + ((size_t)(bh * 16 + p) * 2 + 0) * 4160;
#pragma unroll
    for (int ht = 0; ht < 4; ht++) {
      *(f32x4*)(slot + row0 * 64 + ht * 16 + quad * 4) = o0[ht];
      *(f32x4*)(slot + row1 * 64 + ht * 16 + quad * 4) = o1[ht];
    }
    if (quad == 0) {
      slot[4096 + row0] = lp0;
      slot[4096 + row1] = lp1;
    }
  } else {
    // B phase 1: big tile, remaining key-tiles (includes diagonal). Partial.
    run(g, 16, g + 1);
    float* slot = part + ((size_t)(bh * 16 + p) * 2 + 1) * 4160;
#pragma unroll
    for (int ht = 0; ht < 4; ht++) {
      *(f32x4*)(slot + row0 * 64 + ht * 16 + quad * 4) = o0[ht];
      *(f32x4*)(slot + row1 * 64 + ht * 16 + quad * 4) = o1[ht];
    }
    if (quad == 0) {
      slot[4096 + row0] = lp0;
      slot[4096 + row1] = lp1;
    }

    // B phase 2: small tile, full causal range. Final normalized write.
    run(p, 0, p + 1);
    const float inv0 = 1.f / lp0;
    const float inv1 = 1.f / lp1;
    f16* cp0 = ctx + (size_t)(b * S_ + p * 64 + row0) * D_ + h * HD_ + quad * 4;
    f16* cp1 = ctx + (size_t)(b * S_ + p * 64 + row1) * D_ + h * HD_ + quad * 4;
#pragma unroll
    for (int ht = 0; ht < 4; ht++) {
      f16x4 ov0 = { (f16)(o0[ht][0] * inv0), (f16)(o0[ht][1] * inv0),
                    (f16)(o0[ht][2] * inv0), (f16)(o0[ht][3] * inv0) };
      *(f16x4*)(cp0 + ht * 16) = ov0;
      f16x4 ov1 = { (f16)(o1[ht][0] * inv1), (f16)(o1[ht][1] * inv1),
                    (f16)(o1[ht][2] * inv1), (f16)(o1[ht][3] * inv1) };
      *(f16x4*)(cp1 + ht * 16) = ov1;
    }
  }
}

// ---------------------------------------------------------------------------
extern "C" void kernel_launch(void* const* d_in, const int* in_sizes, int n_in,
                              void* d_out, int out_size, void* d_ws, size_t ws_size,
                              hipStream_t stream) {
  (void)in_sizes; (void)n_in; (void)out_size; (void)ws_size;
  const float* x  = (const float*)d_in[0];
  const float* am = (const float*)d_in[1];
  const float* Wq = (const float*)d_in[2];
  const float* Wk = (const float*)d_in[3];
  const float* Wv = (const float*)d_in[4];
  const float* Wo = (const float*)d_in[5];
  const float* bo = (const float*)d_in[6];
  float* out = (float*)d_out;

  f16* ws   = (f16*)d_ws;
  f16* wqkv = ws;                                   // 3*D*D   (Wq|Wk|Wv, NxK)
  f16* wo16 = wqkv + (size_t)3 * D_ * D_;           // D*D
  f16* xb   = wo16 + (size_t)D_ * D_;               // M*D
  f16* qkvb = xb + (size_t)M_ * D_;                 // M*3D  (Q|K cols used)
  f16* vtb  = qkvb + (size_t)M_ * N3_;              // B*H*HD*S
  f16* ctxb = vtb + (size_t)M_ * D_;                // M*D
  float* part = (float*)(ctxb + (size_t)M_ * D_);   // 512*2*4160 f32 = 17 MB

  const float qscale = 0.125f * 1.4426950408889634f;  // 1/sqrt(hd) * log2(e)

  cvt_all<<<dim3((M_ * D_ + 4 * D_ * D_) / 1024), 256, 0, stream>>>(
      x, Wq, Wk, Wv, Wo, xb, wqkv, qscale);

  gemm_qkv<<<dim3(1536), 256, 0, stream>>>(
      xb, wqkv, qkvb, vtb, am);
  flash_attn8<<<dim3(1024), 128, 0, stream>>>(qkvb, vtb, ctxb, part);
  gemm_proj<<<dim3(512), 256, 0, stream>>>(
      ctxb, wo16, out, bo, part);
}

// Round 15
// 170.027 us; speedup vs baseline: 1.0797x; 1.0797x over previous
//
#include <hip/hip_runtime.h>

// Problem constants
#define B_  2
#define S_  2048
#define D_  1024
#define H_  16
#define HD_ 64
#define N3_ 3072      // 3*D
#define M_  4096      // B*S

typedef _Float16 f16;
typedef _Float16 f16x2 __attribute__((ext_vector_type(2)));
typedef _Float16 f16x4 __attribute__((ext_vector_type(4)));
typedef _Float16 f16x8 __attribute__((ext_vector_type(8)));
typedef float    f32x4 __attribute__((ext_vector_type(4)));

// ---------------------------------------------------------------------------
// async global->LDS, 16B per lane. LDS dest must be wave-uniform base+lane*16.
__device__ __forceinline__ void async16(const f16* g, f16* l) {
  __builtin_amdgcn_global_load_lds(
      (const __attribute__((address_space(1))) unsigned int*)g,
      (__attribute__((address_space(3))) unsigned int*)l, 16, 0, 0);
}

__device__ __forceinline__ f16x2 pkrtz(float a, float b) {
  return __builtin_bit_cast(f16x2, __builtin_amdgcn_cvt_pkrtz(a, b));
}

// Raw v_exp_f32 (2^x). exp2f without fast-math expands to ~6-inst libm
// range-fixup; scores here are bounded and masked lanes (-1e30) flush to 0.
__device__ __forceinline__ float vexp2(float x) {
  float r; asm("v_exp_f32 %0, %1" : "=v"(r) : "v"(x)); return r;
}

// ---------------------------------------------------------------------------
// One launch converts x AND all 4 weight matrices to f16.
__global__ __launch_bounds__(256)
void cvt_all(const float* __restrict__ x,
             const float* __restrict__ Wq, const float* __restrict__ Wk,
             const float* __restrict__ Wv, const float* __restrict__ Wo,
             f16* __restrict__ xb, f16* __restrict__ wdst, float qscale) {
  const int i = blockIdx.x * 256 + threadIdx.x;
  const int XN4 = M_ * D_ / 4;          // 1048576
  const int WN4 = D_ * D_ / 4;          // 262144 = 2^18
  const float* src;
  f16* dst;
  float scale = 1.0f;
  int j;
  if (i < XN4) {
    src = x; dst = xb; j = i;
  } else {
    int k = i - XN4;
    int m = k >> 18;                    // which weight matrix
    j = k & (WN4 - 1);
    src = (m == 0) ? Wq : (m == 1) ? Wk : (m == 2) ? Wv : Wo;
    if (m == 0) scale = qscale;
    dst = wdst + (size_t)m * D_ * D_;
  }
  float4 v = ((const float4*)src)[j];
  f16x4 o = { (f16)(v.x * scale), (f16)(v.y * scale),
              (f16)(v.z * scale), (f16)(v.w * scale) };
  ((f16x4*)dst)[j] = o;
}

// ---------------------------------------------------------------------------
// QKV GEMM v4 (r10 measured-good): 64x128 tile, 48KB dbuf, grid 1536 =
// 6 blocks/CU over 3-resident capacity = two FULL residency rounds, no tail.
// Counted-vmcnt dbuf (vmcnt(6)), raw s_barrier, XCD chunk 16Mx12N.
__global__ __launch_bounds__(256)
void gemm_qkv(const f16* __restrict__ A, const f16* __restrict__ Bw,
              f16* __restrict__ Cq, f16* __restrict__ vtout,
              const float* __restrict__ mask) {
  __shared__ f16 As0[64 * 64];
  __shared__ f16 Bs0[128 * 64];
  __shared__ f16 As1[64 * 64];
  __shared__ f16 Bs1[128 * 64];

  const int tid  = threadIdx.x;
  const int lane = tid & 63;
  const int w    = tid >> 6;
  const int lcol = lane & 15;
  const int quad = lane >> 4;
  const int lx   = lcol & 7;
  const int wave_m = w >> 1, wave_n = w & 1;

  // XCD-chunked swizzle: 1536 = 8 XCDs x 192; per XCD 16 M x 12 N tiles.
  const int lin  = blockIdx.x;
  const int xcd  = lin & 7;
  const int c    = lin >> 3;             // 0..191
  const int mIdx = c / 12;               // 0..15
  const int nIdx = c - mIdx * 12;        // 0..11
  const int m0 = ((xcd >> 1) * 16 + mIdx) * 64;
  const int n0 = ((xcd & 1) * 12 + nIdx) * 128;

  const int rr  = lane >> 3;
  const int gch = (lane & 7) ^ rr;

  const f16* gA[2];
  const f16* gB[4];
#pragma unroll
  for (int i = 0; i < 2; i++) {
    int seg = 2 * w + i;
    gA[i] = A + (size_t)(m0 + seg * 8 + rr) * D_ + gch * 8;
  }
#pragma unroll
  for (int i = 0; i < 4; i++) {
    int seg = i * 4 + w;
    gB[i] = Bw + (size_t)(n0 + seg * 8 + rr) * D_ + gch * 8;
  }

  int offA[2], offB[4];
#pragma unroll
  for (int i = 0; i < 2; i++) offA[i] = (wave_m * 32 + i * 16 + lcol) * 64;
#pragma unroll
  for (int i = 0; i < 4; i++) offB[i] = (wave_n * 64 + i * 16 + lcol) * 64;

  const f32x4 zero = {0.f, 0.f, 0.f, 0.f};
  f32x4 acc[2][4];
#pragma unroll
  for (int i = 0; i < 2; i++)
#pragma unroll
    for (int j = 0; j < 4; j++) acc[i][j] = zero;

  auto stage = [&](int k0, f16* sA, f16* sB) {
#pragma unroll
    for (int i = 0; i < 2; i++) async16(gA[i] + k0, sA + (2 * w + i) * 512);
#pragma unroll
    for (int i = 0; i < 4; i++) async16(gB[i] + k0, sB + (i * 4 + w) * 512);
  };
  auto compute = [&](const f16* sA, const f16* sB) {
#pragma unroll
    for (int ks = 0; ks < 2; ks++) {
      const int co = ((quad + 4 * ks) ^ lx) * 8;
      f16x8 af[2], bf[4];
#pragma unroll
      for (int i = 0; i < 2; i++) af[i] = *(const f16x8*)(sA + offA[i] + co);
#pragma unroll
      for (int i = 0; i < 4; i++) bf[i] = *(const f16x8*)(sB + offB[i] + co);
#pragma unroll
      for (int mi = 0; mi < 2; mi++)
#pragma unroll
        for (int ni = 0; ni < 4; ni++)
          acc[mi][ni] = __builtin_amdgcn_mfma_f32_16x16x32_f16(
              af[mi], bf[ni], acc[mi][ni], 0, 0, 0);
    }
  };

  // K pipeline: 16 tiles of BK=64, even->buf0, odd->buf1. Each stage issues
  // 6 loads/wave; vmcnt(6) waits for the PREVIOUS stage's 6 (issued one full
  // compute phase earlier). Every wave waits before s_barrier, so the buffer
  // is complete device-wide.
  stage(0, As0, Bs0);
  for (int it = 0; it < 14; it += 2) {
    stage((it + 1) * 64, As1, Bs1);
    asm volatile("s_waitcnt vmcnt(6)\ns_barrier" ::: "memory");
    compute(As0, Bs0);
    asm volatile("s_barrier" ::: "memory");      // buf0 readers done
    stage((it + 2) * 64, As0, Bs0);
    asm volatile("s_waitcnt vmcnt(6)\ns_barrier" ::: "memory");
    compute(As1, Bs1);
    asm volatile("s_barrier" ::: "memory");      // buf1 readers done
  }
  stage(15 * 64, As1, Bs1);
  asm volatile("s_waitcnt vmcnt(6)\ns_barrier" ::: "memory");
  compute(As0, Bs0);                              // tile 14
  asm volatile("s_waitcnt vmcnt(0)\ns_barrier" ::: "memory");
  compute(As1, Bs1);                              // tile 15

  // Epilogue: n0 is a multiple of 128 -> whole tile in one region.
#pragma unroll
  for (int mi = 0; mi < 2; mi++) {
    const int mgb = m0 + wave_m * 32 + mi * 16 + quad * 4;
    const int bb = mgb >> 11, s = mgb & (S_ - 1);
    const float mk0 = mask[mgb], mk1 = mask[mgb + 1];
    const float mk2 = mask[mgb + 2], mk3 = mask[mgb + 3];
    const float mks[4] = {mk0, mk1, mk2, mk3};
    if (n0 >= 2 * D_) {
      // V column-block: fused transpose with pad mask.
#pragma unroll
      for (int ni = 0; ni < 4; ni++) {
        const int vcol = n0 - 2 * D_ + wave_n * 64 + ni * 16 + lcol;
        f16x4 v = { (f16)(acc[mi][ni][0] * mk0), (f16)(acc[mi][ni][1] * mk1),
                    (f16)(acc[mi][ni][2] * mk2), (f16)(acc[mi][ni][3] * mk3) };
        *(f16x4*)(vtout +
                  ((size_t)(bb * 16 + (vcol >> 6)) * 64 + (vcol & 63)) * S_ + s) = v;
      }
    } else {
      const bool kmask = (n0 >= D_);
#pragma unroll
      for (int r = 0; r < 4; r++) {
        const float mk = kmask ? mks[r] : 1.0f;
#pragma unroll
        for (int ni = 0; ni < 4; ni++) {
          int ng = n0 + wave_n * 64 + ni * 16 + lcol;
          Cq[(size_t)(mgb + r) * N3_ + ng] = (f16)(acc[mi][ni][r] * mk);
        }
      }
    }
  }
}

// ---------------------------------------------------------------------------
// Output-projection GEMM v2 (r11 measured-good): counted-vmcnt dbuf +
// XCD-chunked swizzle (per XCD 16M x 4N). 48KB dbuf, grid 512.
// r14 lesson: fusing attn_combine into this kernel REGRESSED (+9us) — the
// combine's f32 reads + VALU + LDS writes sat exposed on a de-pipelined
// critical path. Fusion into a pipelined GEMM only pays if the fused work
// rides the existing async pipeline.
__global__ __launch_bounds__(256)
void gemm_proj(const f16* __restrict__ A, const f16* __restrict__ Bw,
               float* __restrict__ Cf, const float* __restrict__ bias) {
  __shared__ f16 As0[64 * 64];
  __shared__ f16 Bs0[128 * 64];
  __shared__ f16 As1[64 * 64];
  __shared__ f16 Bs1[128 * 64];

  const int tid  = threadIdx.x;
  const int lane = tid & 63;
  const int w    = tid >> 6;
  const int lcol = lane & 15;
  const int quad = lane >> 4;
  const int lx   = lcol & 7;
  const int wave_m = w >> 1, wave_n = w & 1;

  // XCD-chunked swizzle: 512 = 8 XCDs x 64; per XCD 16 M x 4 N tiles.
  const int lin  = blockIdx.x;
  const int xcd  = lin & 7;
  const int c    = lin >> 3;             // 0..63
  const int mIdx = c >> 2;               // 0..15
  const int nIdx = c & 3;                // 0..3
  const int m0 = ((xcd >> 1) * 16 + mIdx) * 64;
  const int n0 = ((xcd & 1) * 4 + nIdx) * 128;

  const int rr  = lane >> 3;
  const int gch = (lane & 7) ^ rr;

  const f16* gA[2];
  const f16* gB[4];
#pragma unroll
  for (int i = 0; i < 2; i++) {
    int seg = 2 * w + i;
    gA[i] = A + (size_t)(m0 + seg * 8 + rr) * D_ + gch * 8;
  }
#pragma unroll
  for (int i = 0; i < 4; i++) {
    int seg = i * 4 + w;
    gB[i] = Bw + (size_t)(n0 + seg * 8 + rr) * D_ + gch * 8;
  }

  int offA[2], offB[4];
#pragma unroll
  for (int i = 0; i < 2; i++) offA[i] = (wave_m * 32 + i * 16 + lcol) * 64;
#pragma unroll
  for (int i = 0; i < 4; i++) offB[i] = (wave_n * 64 + i * 16 + lcol) * 64;

  const f32x4 zero = {0.f, 0.f, 0.f, 0.f};
  f32x4 acc[2][4];
#pragma unroll
  for (int i = 0; i < 2; i++)
#pragma unroll
    for (int j = 0; j < 4; j++) acc[i][j] = zero;

  auto stage = [&](int k0, f16* sA, f16* sB) {
#pragma unroll
    for (int i = 0; i < 2; i++) async16(gA[i] + k0, sA + (2 * w + i) * 512);
#pragma unroll
    for (int i = 0; i < 4; i++) async16(gB[i] + k0, sB + (i * 4 + w) * 512);
  };
  auto compute = [&](const f16* sA, const f16* sB) {
#pragma unroll
    for (int ks = 0; ks < 2; ks++) {
      const int co = ((quad + 4 * ks) ^ lx) * 8;
      f16x8 af[2], bf[4];
#pragma unroll
      for (int i = 0; i < 2; i++) af[i] = *(const f16x8*)(sA + offA[i] + co);
#pragma unroll
      for (int i = 0; i < 4; i++) bf[i] = *(const f16x8*)(sB + offB[i] + co);
#pragma unroll
      for (int mi = 0; mi < 2; mi++)
#pragma unroll
        for (int ni = 0; ni < 4; ni++)
          acc[mi][ni] = __builtin_amdgcn_mfma_f32_16x16x32_f16(
              af[mi], bf[ni], acc[mi][ni], 0, 0, 0);
    }
  };

  stage(0, As0, Bs0);
  for (int it = 0; it < 14; it += 2) {
    stage((it + 1) * 64, As1, Bs1);
    asm volatile("s_waitcnt vmcnt(6)\ns_barrier" ::: "memory");
    compute(As0, Bs0);
    asm volatile("s_barrier" ::: "memory");      // buf0 readers done
    stage((it + 2) * 64, As0, Bs0);
    asm volatile("s_waitcnt vmcnt(6)\ns_barrier" ::: "memory");
    compute(As1, Bs1);
    asm volatile("s_barrier" ::: "memory");      // buf1 readers done
  }
  stage(15 * 64, As1, Bs1);
  asm volatile("s_waitcnt vmcnt(6)\ns_barrier" ::: "memory");
  compute(As0, Bs0);                              // tile 14
  asm volatile("s_waitcnt vmcnt(0)\ns_barrier" ::: "memory");
  compute(As1, Bs1);                              // tile 15

#pragma unroll
  for (int mi = 0; mi < 2; mi++) {
#pragma unroll
    for (int r = 0; r < 4; r++) {
      int mg = m0 + wave_m * 32 + mi * 16 + quad * 4 + r;
#pragma unroll
      for (int ni = 0; ni < 4; ni++) {
        int ng = n0 + wave_n * 64 + ni * 16 + lcol;
        Cf[(size_t)mg * D_ + ng] = acc[mi][ni][r] + bias[ng];
      }
    }
  }
}

// ---------------------------------------------------------------------------
// Flash attention v8 (r11/r13 measured-best): 32 q-rows PER WAVE (2
// q-subtiles), 2 waves per block (128 threads). K/V fragments are
// q-independent -> each LDS fragment read feeds TWO MFMA pairs. Raw
// v_exp_f32 softmax. Grid 1024, A/B equal-work role split, XCD swizzle on
// id&31, separate combine kernel (fusion regressed, r14).
__global__ __launch_bounds__(128)
void flash_attn8(const f16* __restrict__ qkv, const f16* __restrict__ vt,
                 f16* __restrict__ ctx, float* __restrict__ part) {
  __shared__ f16 Ks[64 * 64];   // [key][hd], 128B rows, chunk-swizzled
  __shared__ f16 Vs[64 * 64];   // [hd][key]

  const int tid  = threadIdx.x;
  const int lane = tid & 63;
  const int w    = tid >> 6;     // 0..1
  const int lcol = lane & 15;
  const int quad = lane >> 4;
  const int lx   = lcol & 7;

  const int id   = blockIdx.x;
  const int bh   = (id & 7) + 8 * ((id >> 3) & 3);  // XCD swizzle (id&31 only)
  const int u    = id >> 5;          // 0..31
  const int p    = u & 15;           // pair index
  const int role = u >> 4;           // 0 = A, 1 = B
  const int g    = 31 - p;           // big q-supertile (>= 16)
  const int b    = bh >> 4, h = bh & 15;

  const int rsub = lane >> 3;
  const int gch  = (lane & 7) ^ rsub;
  const f16* Kg = qkv + (size_t)b * S_ * N3_ + D_ + h * HD_;  // row stride N3
  const f16* Vg = vt + (size_t)bh * HD_ * S_;                 // row stride S

  // This wave stages 4 of the 8 row-groups (8 rows each) of K and V.
  int srow[4];
  f16 *ldsK[4], *ldsV[4];
#pragma unroll
  for (int i = 0; i < 4; i++) {
    const int r0 = w * 32 + i * 8;
    srow[i] = r0 + rsub;
    ldsK[i] = Ks + r0 * 64;
    ldsV[i] = Vs + r0 * 64;
  }

  const f32x4 zero = {0.f, 0.f, 0.f, 0.f};
  f32x4 o0[4], o1[4];
  float lp0, lp1;

  auto run = [&](int qt, int ktb, int kte) {
    const int qrow0 = qt * 64 + w * 32 + lcol;        // subtile 0
    const int qrow1 = qrow0 + 16;                     // subtile 1
    const f16* Qp0 = qkv + (size_t)(b * S_ + qrow0) * N3_ + h * HD_;
    const f16* Qp1 = qkv + (size_t)(b * S_ + qrow1) * N3_ + h * HD_;
    const f16x8 qa0 = *(const f16x8*)(Qp0 + quad * 8);
    const f16x8 qa1 = *(const f16x8*)(Qp0 + 32 + quad * 8);
    const f16x8 qb0 = *(const f16x8*)(Qp1 + quad * 8);
    const f16x8 qb1 = *(const f16x8*)(Qp1 + 32 + quad * 8);
#pragma unroll
    for (int i = 0; i < 4; i++) { o0[i] = zero; o1[i] = zero; }
    lp0 = 0.f; lp1 = 0.f;

    for (int kt = ktb; kt < kte; kt++) {
      const int kbase = kt * 64;
      __syncthreads();
#pragma unroll
      for (int i = 0; i < 4; i++)
        async16(Kg + (size_t)(kbase + srow[i]) * N3_ + gch * 8, ldsK[i]);
#pragma unroll
      for (int i = 0; i < 4; i++)
        async16(Vg + (size_t)srow[i] * S_ + kbase + gch * 8, ldsV[i]);
      __syncthreads();

      f32x4 sc0[4], sc1[4];
#pragma unroll
      for (int ct = 0; ct < 4; ct++) {
        const f16* kr = Ks + (ct * 16 + lcol) * 64;
        f16x8 kf0 = *(const f16x8*)(kr + ((quad    ) ^ lx) * 8);
        f16x8 kf1 = *(const f16x8*)(kr + ((quad + 4) ^ lx) * 8);
        f32x4 z0 = zero;
        z0 = __builtin_amdgcn_mfma_f32_16x16x32_f16(kf0, qa0, z0, 0, 0, 0);
        z0 = __builtin_amdgcn_mfma_f32_16x16x32_f16(kf1, qa1, z0, 0, 0, 0);
        sc0[ct] = z0;
        f32x4 z1 = zero;
        z1 = __builtin_amdgcn_mfma_f32_16x16x32_f16(kf0, qb0, z1, 0, 0, 0);
        z1 = __builtin_amdgcn_mfma_f32_16x16x32_f16(kf1, qb1, z1, 0, 0, 0);
        sc1[ct] = z1;
      }

      if (kt == qt) {
        const int qoff0 = w * 32 + lcol;
        const int qoff1 = qoff0 + 16;
#pragma unroll
        for (int ct = 0; ct < 4; ct++) {
          const int koff = ct * 16 + quad * 4;
#pragma unroll
          for (int r = 0; r < 4; r++) {
            if (koff + r > qoff0) sc0[ct][r] = -1e30f;
            if (koff + r > qoff1) sc1[ct][r] = -1e30f;
          }
        }
      }

      f16x4 pf0[4], pf1[4];
#pragma unroll
      for (int ct = 0; ct < 4; ct++) {
        float a0 = vexp2(sc0[ct][0]), a1 = vexp2(sc0[ct][1]);
        float a2 = vexp2(sc0[ct][2]), a3 = vexp2(sc0[ct][3]);
        lp0 += (a0 + a1) + (a2 + a3);
        f16x2 alo = pkrtz(a0, a1);
        f16x2 ahi = pkrtz(a2, a3);
        f16x4 pa = { alo[0], alo[1], ahi[0], ahi[1] };
        pf0[ct] = pa;
        float b0 = vexp2(sc1[ct][0]), b1 = vexp2(sc1[ct][1]);
        float b2 = vexp2(sc1[ct][2]), b3 = vexp2(sc1[ct][3]);
        lp1 += (b0 + b1) + (b2 + b3);
        f16x2 blo = pkrtz(b0, b1);
        f16x2 bhi = pkrtz(b2, b3);
        f16x4 pb = { blo[0], blo[1], bhi[0], bhi[1] };
        pf1[ct] = pb;
      }

#pragma unroll
      for (int ht = 0; ht < 4; ht++) {
        const f16* vr = Vs + (ht * 16 + lcol) * 64 + (quad & 1) * 4;
#pragma unroll
        for (int ct = 0; ct < 4; ct++) {
          f16x4 vf = *(const f16x4*)(vr + (((2 * ct + (quad >> 1)) ^ lx) * 8));
          o0[ht] = __builtin_amdgcn_mfma_f32_16x16x16f16(vf, pf0[ct], o0[ht], 0, 0, 0);
          o1[ht] = __builtin_amdgcn_mfma_f32_16x16x16f16(vf, pf1[ct], o1[ht], 0, 0, 0);
        }
      }
    }
    lp0 += __shfl_xor(lp0, 16);
    lp0 += __shfl_xor(lp0, 32);
    lp1 += __shfl_xor(lp1, 16);
    lp1 += __shfl_xor(lp1, 32);
  };

  const int row0 = w * 32 + lcol;          // row within 64-row tile, sub 0
  const int row1 = row0 + 16;              // sub 1

  if (role == 0) {
    // A: big tile, first 16 key-tiles (never diagonal). Partial out.
    run(g, 0, 16);
    float* slot = part + ((size_t)(bh * 16 + p) * 2 + 0) * 4160;
#pragma unroll
    for (int ht = 0; ht < 4; ht++) {
      *(f32x4*)(slot + row0 * 64 + ht * 16 + quad * 4) = o0[ht];
      *(f32x4*)(slot + row1 * 64 + ht * 16 + quad * 4) = o1[ht];
    }
    if (quad == 0) {
      slot[4096 + row0] = lp0;
      slot[4096 + row1] = lp1;
    }
  } else {
    // B phase 1: big tile, remaining key-tiles (includes diagonal). Partial.
    run(g, 16, g + 1);
    float* slot = part + ((size_t)(bh * 16 + p) * 2 + 1) * 4160;
#pragma unroll
    for (int ht = 0; ht < 4; ht++) {
      *(f32x4*)(slot + row0 * 64 + ht * 16 + quad * 4) = o0[ht];
      *(f32x4*)(slot + row1 * 64 + ht * 16 + quad * 4) = o1[ht];
    }
    if (quad == 0) {
      slot[4096 + row0] = lp0;
      slot[4096 + row1] = lp1;
    }

    // B phase 2: small tile, full causal range. Final normalized write.
    run(p, 0, p + 1);
    const float inv0 = 1.f / lp0;
    const float inv1 = 1.f / lp1;
    f16* cp0 = ctx + (size_t)(b * S_ + p * 64 + row0) * D_ + h * HD_ + quad * 4;
    f16* cp1 = ctx + (size_t)(b * S_ + p * 64 + row1) * D_ + h * HD_ + quad * 4;
#pragma unroll
    for (int ht = 0; ht < 4; ht++) {
      f16x4 ov0 = { (f16)(o0[ht][0] * inv0), (f16)(o0[ht][1] * inv0),
                    (f16)(o0[ht][2] * inv0), (f16)(o0[ht][3] * inv0) };
      *(f16x4*)(cp0 + ht * 16) = ov0;
      f16x4 ov1 = { (f16)(o1[ht][0] * inv1), (f16)(o1[ht][1] * inv1),
                    (f16)(o1[ht][2] * inv1), (f16)(o1[ht][3] * inv1) };
      *(f16x4*)(cp1 + ht * 16) = ov1;
    }
  }
}

// ---------------------------------------------------------------------------
// Combine partials for the big tiles: ctx = (oA+oB)/(lpA+lpB), cast f16.
// Grid 512 = one block per (bh, pair). Deterministic, stream-ordered.
__global__ __launch_bounds__(256)
void attn_combine(const float* __restrict__ part, f16* __restrict__ ctx) {
  const int sid = blockIdx.x;            // bh*16 + p
  const int bh  = sid >> 4, p = sid & 15;
  const int g   = 31 - p;
  const int b   = bh >> 4, h = bh & 15;
  const int t   = threadIdx.x;
  const int row = t >> 2;                // 0..63
  const int c0  = (t & 3) * 16;          // hd base

  const float* sA = part + ((size_t)sid * 2 + 0) * 4160;
  const float* sB = part + ((size_t)sid * 2 + 1) * 4160;
  const float inv = 1.f / (sA[4096 + row] + sB[4096 + row]);
  const int qrow = g * 64 + row;
  f16* cp = ctx + (size_t)(b * S_ + qrow) * D_ + h * HD_ + c0;
#pragma unroll
  for (int j0 = 0; j0 < 16; j0 += 4) {
    f32x4 a  = *(const f32x4*)(sA + row * 64 + c0 + j0);
    f32x4 bb = *(const f32x4*)(sB + row * 64 + c0 + j0);
    f16x4 ov = { (f16)((a[0] + bb[0]) * inv), (f16)((a[1] + bb[1]) * inv),
                 (f16)((a[2] + bb[2]) * inv), (f16)((a[3] + bb[3]) * inv) };
    *(f16x4*)(cp + j0) = ov;
  }
}

// ---------------------------------------------------------------------------
extern "C" void kernel_launch(void* const* d_in, const int* in_sizes, int n_in,
                              void* d_out, int out_size, void* d_ws, size_t ws_size,
                              hipStream_t stream) {
  (void)in_sizes; (void)n_in; (void)out_size; (void)ws_size;
  const float* x  = (const float*)d_in[0];
  const float* am = (const float*)d_in[1];
  const float* Wq = (const float*)d_in[2];
  const float* Wk = (const float*)d_in[3];
  const float* Wv = (const float*)d_in[4];
  const float* Wo = (const float*)d_in[5];
  const float* bo = (const float*)d_in[6];
  float* out = (float*)d_out;

  f16* ws   = (f16*)d_ws;
  f16* wqkv = ws;                                   // 3*D*D   (Wq|Wk|Wv, NxK)
  f16* wo16 = wqkv + (size_t)3 * D_ * D_;           // D*D
  f16* xb   = wo16 + (size_t)D_ * D_;               // M*D
  f16* qkvb = xb + (size_t)M_ * D_;                 // M*3D  (Q|K cols used)
  f16* vtb  = qkvb + (size_t)M_ * N3_;              // B*H*HD*S
  f16* ctxb = vtb + (size_t)M_ * D_;                // M*D
  float* part = (float*)(ctxb + (size_t)M_ * D_);   // 512*2*4160 f32 = 17 MB

  const float qscale = 0.125f * 1.4426950408889634f;  // 1/sqrt(hd) * log2(e)

  cvt_all<<<dim3((M_ * D_ + 4 * D_ * D_) / 1024), 256, 0, stream>>>(
      x, Wq, Wk, Wv, Wo, xb, wqkv, qscale);

  gemm_qkv<<<dim3(1536), 256, 0, stream>>>(
      xb, wqkv, qkvb, vtb, am);
  flash_attn8<<<dim3(1024), 128, 0, stream>>>(qkvb, vtb, ctxb, part);
  attn_combine<<<dim3(512), 256, 0, stream>>>(part, ctxb);
  gemm_proj<<<dim3(512), 256, 0, stream>>>(
      ctxb, wo16, out, bo);
}